// Round 3
// baseline (364.365 us; speedup 1.0000x reference)
//
#include <hip/hip_runtime.h>
#include <math.h>

#define N_RES 1024
#define N_ATOMS 37
#define ATOM_CA 1
#define NBATCH 256
#define BLOCKS 1024           // 4 blocks per batch, 256 residues each
#define SLICES 4              // partial rows per batch
#define NSUM 18
// Scatter loads (12B @ 444B stride) run at 0.53 TB/s (MSHR/latency-bound,
// measured round 2: 51 MB fetched in 100 us, VALUBusy 0.6%). Contiguous
// float4 streaming runs at ~6.3 TB/s. So we STREAM the full arrays
// (262 MB, 5x the bytes) through LDS and extract CA there: ~45 us model.
//
// sums layout per partial row:
// 0: M    1-3: Sp    4-6: St    7: Qp    8: Qt    9-17: Cpt[i][j]
// Workspace: float partials[1024][18] (73728 B), then uint ticket (4 B).

// Per-block tile: 256 contiguous residues of one batch, staged in quarters
// of 64 residues. Coord quarter = 64*111 floats = 28416 B; mask quarter =
// 64*37 floats = 9472 B. Quarter bases are 16B-aligned (64*444 = 28416 and
// 64*148 = 9472 are both multiples of 16). LDS extract stride 111 floats:
// bank = (111*i+3) % 32 = (15*i+3) % 32, 15 coprime 32 -> 2-way (free).
#define CQ_F4 1776            // 28416 B / 16
#define MQ_F4 592             // 9472 B / 16

__global__ __launch_bounds__(256) void rmsd_fused_kernel(
    const float* __restrict__ pred, const float* __restrict__ truec,
    const float* __restrict__ mask, float* __restrict__ partials,
    unsigned int* __restrict__ ticket, float* __restrict__ out)
{
    const int blk = blockIdx.x;        // 0..1023
    const int b   = blk >> 2;          // batch
    const int s   = blk & 3;           // tile-of-256 within batch
    const int tid = threadIdx.x;
    const int wq  = tid >> 6;          // wave id == the quarter this wave owns
    const int i   = tid & 63;          // residue index within the quarter

    __shared__ __align__(16) float cbuf[CQ_F4 * 4];  // 28416 B coord quarter
    __shared__ __align__(16) float mbuf[MQ_F4 * 4];  // 9472 B mask quarter

    const size_t resBase = (size_t)b * N_RES + (size_t)s * 256;
    const int    eb = i * 111 + 3;     // CA triple offset within coord quarter
    const int    mb = i * 37 + ATOM_CA;

    float m = 0.f, p0 = 0.f, p1 = 0.f, p2 = 0.f, t0 = 0.f, t1 = 0.f, t2 = 0.f;

    // ---- stream pred + mask quarters through LDS, extract CA ----
#pragma unroll
    for (int q = 0; q < 4; ++q) {
        const float4* pq = reinterpret_cast<const float4*>(pred + (resBase + 64u*q) * 111);
        const float4* mq = reinterpret_cast<const float4*>(mask + (resBase + 64u*q) * 37);
        float4* c4 = reinterpret_cast<float4*>(cbuf);
        float4* m4 = reinterpret_cast<float4*>(mbuf);
        __syncthreads();               // WAR: previous quarter's readers done
        for (int idx = tid; idx < CQ_F4 + MQ_F4; idx += 256) {
            if (idx < CQ_F4) c4[idx] = pq[idx];
            else             m4[idx - CQ_F4] = mq[idx - CQ_F4];
        }
        __syncthreads();
        if (wq == q) {                 // wave-uniform: zero divergence
            p0 = cbuf[eb]; p1 = cbuf[eb + 1]; p2 = cbuf[eb + 2];
            m  = mbuf[mb];
        }
    }
    // ---- stream true quarters through the same LDS buffer ----
#pragma unroll
    for (int q = 0; q < 4; ++q) {
        const float4* tq = reinterpret_cast<const float4*>(truec + (resBase + 64u*q) * 111);
        float4* c4 = reinterpret_cast<float4*>(cbuf);
        __syncthreads();
        for (int idx = tid; idx < CQ_F4; idx += 256) c4[idx] = tq[idx];
        __syncthreads();
        if (wq == q) {
            t0 = cbuf[eb]; t1 = cbuf[eb + 1]; t2 = cbuf[eb + 2];
        }
    }

    // ---- per-thread moments (binary mask => m^2 == m) ----
    float acc[NSUM];
    acc[0] = m;
    acc[1] = m * p0;  acc[2] = m * p1;  acc[3] = m * p2;
    acc[4] = m * t0;  acc[5] = m * t1;  acc[6] = m * t2;
    acc[7] = m * (p0*p0 + p1*p1 + p2*p2);
    acc[8] = m * (t0*t0 + t1*t1 + t2*t2);
    acc[9]  = m * p0 * t0; acc[10] = m * p0 * t1; acc[11] = m * p0 * t2;
    acc[12] = m * p1 * t0; acc[13] = m * p1 * t1; acc[14] = m * p1 * t2;
    acc[15] = m * p2 * t0; acc[16] = m * p2 * t1; acc[17] = m * p2 * t2;

    // wave(64) shuffle reduce
#pragma unroll
    for (int k = 0; k < NSUM; ++k) {
        float v = acc[k];
#pragma unroll
        for (int off = 32; off > 0; off >>= 1) v += __shfl_down(v, off, 64);
        acc[k] = v;
    }

    __shared__ float partial[4][NSUM];
    if (i == 0) {
#pragma unroll
        for (int k = 0; k < NSUM; ++k) partial[wq][k] = acc[k];
    }
    __syncthreads();
    if (tid < NSUM) {
        partials[(size_t)blk * NSUM + tid] =
            partial[0][tid] + partial[1][tid] + partial[2][tid] + partial[3][tid];
    }

    // ---- last-block-done handoff (device-scope, XCD-safe) ----
    __threadfence();
    __syncthreads();
    __shared__ bool amLast;
    if (tid == 0)
        amLast = (atomicAdd(ticket, 1u) == (unsigned)(gridDim.x - 1));
    __syncthreads();
    if (!amLast) return;
    __threadfence();

    // ---- finish: thread b = batch b. Theobald QCP, fp64, register-only ----
    {
        const int bb = tid;
        double sm[NSUM];
#pragma unroll
        for (int k = 0; k < NSUM; ++k) sm[k] = 0.0;
#pragma unroll
        for (int k = 0; k < SLICES; ++k) {
            const float* row = partials + ((size_t)bb * SLICES + k) * NSUM;
#pragma unroll
            for (int j = 0; j < NSUM; ++j) sm[j] += (double)row[j];
        }

        const double M   = sm[0];
        const double Mep = M + 1e-8;
        const double Sp0 = sm[1], Sp1 = sm[2], Sp2 = sm[3];
        const double St0 = sm[4], St1 = sm[5], St2 = sm[6];
        const double pc0 = Sp0 / Mep, pc1 = Sp1 / Mep, pc2 = Sp2 / Mep;
        const double tc0 = St0 / Mep, tc1 = St1 / Mep, tc2 = St2 / Mep;
        const double Qp = sm[7], Qt = sm[8];

        const double Sxx = sm[9]  - pc0 * St0 - tc0 * Sp0 + pc0 * tc0 * M;
        const double Sxy = sm[10] - pc0 * St1 - tc1 * Sp0 + pc0 * tc1 * M;
        const double Sxz = sm[11] - pc0 * St2 - tc2 * Sp0 + pc0 * tc2 * M;
        const double Syx = sm[12] - pc1 * St0 - tc0 * Sp1 + pc1 * tc0 * M;
        const double Syy = sm[13] - pc1 * St1 - tc1 * Sp1 + pc1 * tc1 * M;
        const double Syz = sm[14] - pc1 * St2 - tc2 * Sp1 + pc1 * tc2 * M;
        const double Szx = sm[15] - pc2 * St0 - tc0 * Sp2 + pc2 * tc0 * M;
        const double Szy = sm[16] - pc2 * St1 - tc1 * Sp2 + pc2 * tc1 * M;
        const double Szz = sm[17] - pc2 * St2 - tc2 * Sp2 + pc2 * tc2 * M;

        const double Qpc = Qp - 2.0*(pc0*Sp0 + pc1*Sp1 + pc2*Sp2)
                         + (pc0*pc0 + pc1*pc1 + pc2*pc2) * M;
        const double Qtc = Qt - 2.0*(tc0*St0 + tc1*St1 + tc2*St2)
                         + (tc0*tc0 + tc1*tc1 + tc2*tc2) * M;

        // ---- QCP characteristic quartic: x^4 + C2 x^2 + C1 x + C0 ----
        const double Sxx2 = Sxx*Sxx, Syy2 = Syy*Syy, Szz2 = Szz*Szz;
        const double Sxy2 = Sxy*Sxy, Syz2 = Syz*Syz, Sxz2 = Sxz*Sxz;
        const double Syx2 = Syx*Syx, Szy2 = Szy*Szy, Szx2 = Szx*Szx;

        const double SyzSzymSyySzz2 = 2.0*(Syz*Szy - Syy*Szz);
        const double Sxx2Syy2Szz2Syz2Szy2 = Syy2 + Szz2 - Sxx2 + Syz2 + Szy2;

        const double C2 = -2.0*(Sxx2 + Syy2 + Szz2 + Sxy2 + Syx2 + Sxz2 + Szx2 + Syz2 + Szy2);
        const double C1 = 8.0*(Sxx*Syz*Szy + Syy*Szx*Sxz + Szz*Sxy*Syx
                             - Sxx*Syy*Szz - Syz*Szx*Sxy - Szy*Syx*Sxz);

        const double SxzpSzx = Sxz + Szx;
        const double SyzpSzy = Syz + Szy;
        const double SxypSyx = Sxy + Syx;
        const double SyzmSzy = Syz - Szy;
        const double SxzmSzx = Sxz - Szx;
        const double SxymSyx = Sxy - Syx;
        const double SxxpSyy = Sxx + Syy;
        const double SxxmSyy = Sxx - Syy;
        const double Sxy2Sxz2Syx2Szx2 = Sxy2 + Sxz2 - Syx2 - Szx2;

        const double C0 =
            Sxy2Sxz2Syx2Szx2 * Sxy2Sxz2Syx2Szx2
          + (Sxx2Syy2Szz2Syz2Szy2 + SyzSzymSyySzz2) * (Sxx2Syy2Szz2Syz2Szy2 - SyzSzymSyySzz2)
          + (-(SxzpSzx)*(SyzmSzy) + (SxymSyx)*(SxxmSyy - Szz)) *
            (-(SxzmSzx)*(SyzpSzy) + (SxymSyx)*(SxxmSyy + Szz))
          + (-(SxzpSzx)*(SyzpSzy) - (SxypSyx)*(SxxpSyy - Szz)) *
            (-(SxzmSzx)*(SyzmSzy) - (SxypSyx)*(SxxpSyy + Szz))
          + ( (SxypSyx)*(SyzpSzy) + (SxzpSzx)*(SxxmSyy + Szz)) *
            (-(SxymSyx)*(SyzmSzy) + (SxzpSzx)*(SxxpSyy + Szz))
          + ( (SxypSyx)*(SyzmSzy) + (SxzmSzx)*(SxxmSyy - Szz)) *
            (-(SxymSyx)*(SyzpSzy) + (SxzmSzx)*(SxxpSyy - Szz));

        // Newton from above: lambda0 = (Qpc+Qtc)/2 >= lambda_max.
        double lam = 0.5 * (Qpc + Qtc);
#pragma unroll
        for (int it = 0; it < 16; ++it) {
            const double x2 = lam * lam;
            const double bq = (x2 + C2) * lam;
            const double aq = bq + C1;
            const double den = 2.0 * x2 * lam + bq + aq;
            const double num = aq * lam + C0;
            const double d = (fabs(den) > 1e-300) ? (num / den) : 0.0;
            lam -= d;
        }

        double D = Qpc + Qtc - 2.0 * lam;
        if (D < 0.0) D = 0.0;
        float rmsd = (float)sqrt(D / Mep);

        // mean over 256 batches
#pragma unroll
        for (int off = 32; off > 0; off >>= 1) rmsd += __shfl_down(rmsd, off, 64);
        __shared__ float part[4];
        if ((tid & 63) == 0) part[tid >> 6] = rmsd;
        __syncthreads();
        if (tid == 0)
            out[0] = (part[0] + part[1] + part[2] + part[3]) * (1.0f / (float)NBATCH);
    }
}

extern "C" void kernel_launch(void* const* d_in, const int* in_sizes, int n_in,
                              void* d_out, int out_size, void* d_ws, size_t ws_size,
                              hipStream_t stream) {
    const float* pred  = (const float*)d_in[0];
    const float* truec = (const float*)d_in[1];
    const float* mask  = (const float*)d_in[2];
    float* out = (float*)d_out;
    float* partials = (float*)d_ws;                       // 1024*18 floats = 73728 B
    unsigned int* ticket = (unsigned int*)((char*)d_ws + BLOCKS * NSUM * sizeof(float));

    // Graph-capturable (memset node); guarantees ticket==0 on every replay.
    hipMemsetAsync(ticket, 0, sizeof(unsigned int), stream);
    rmsd_fused_kernel<<<BLOCKS, 256, 0, stream>>>(
        pred, truec, mask, partials, ticket, out);
}